// Round 3
// baseline (210.559 us; speedup 1.0000x reference)
//
#include <hip/hip_runtime.h>

#define N 8192
#define D 64
#define JSPLIT 16
#define JSTEPS (N / 64 / JSPLIT)   // 8 J-tiles of 64 cols per block

typedef unsigned short ushort_t;
typedef __attribute__((ext_vector_type(8))) short bf16x8;
typedef __attribute__((ext_vector_type(4))) float f32x4;

#define TWO_OVER_LN2 2.885390081777927f   // exp(2x) == exp2(x * 2/ln2)

#if __has_builtin(__builtin_amdgcn_exp2f)
#define EXP2F(x) __builtin_amdgcn_exp2f(x)
#else
#define EXP2F(x) exp2f(x)
#endif

typedef __attribute__((address_space(1))) const unsigned int g_u32;
typedef __attribute__((address_space(3))) unsigned int       l_u32;

__device__ inline ushort_t f32_to_bf16(float f) {
    union { float f; unsigned u; } c; c.f = f;
    unsigned r = (c.u + 0x7FFFu + ((c.u >> 16) & 1u)) >> 16;
    return (ushort_t)r;
}

// ---------------- kernel 1: L2-normalize rows, emit bf16 ----------------
__global__ void normalize_kernel(const float* __restrict__ z_mp,
                                 const float* __restrict__ z_sc,
                                 ushort_t* __restrict__ zn) {
    int lane = threadIdx.x & 63;
    int row  = blockIdx.x * 4 + (threadIdx.x >> 6);
    const float* src = (row < N) ? z_mp : z_sc;
    int srow = row & (N - 1);
    float x = src[srow * D + lane];
    float s = x * x;
    #pragma unroll
    for (int m = 32; m; m >>= 1) s += __shfl_xor(s, m, 64);
    float n = sqrtf(s);
    float scale = 1.0f / fmaxf(n, 1e-12f);
    zn[row * D + lane] = f32_to_bf16(x * scale);
}

// ---------------- kernel 2: tiled 4-pair similarity + row accumulation --
// 4 waves/block, wave w computes term (a=w>>1, b=w&1) on the SAME 64x64
// (I,J) tile, so the pos tile is staged to LDS once and shared.
// Column permutation: B-fragment c <- zn row (Jc + 4*lcol + c), so a lane's
// 4 output columns are contiguous -> pos reads are f32x4.
// Async 2-phase pipeline: stage pos[jj+1] via global_load_lds + prefetch
// B-frags[jj+1] to regs BEFORE computing jj; one barrier per jj.
__global__ __launch_bounds__(256, 2) void contrast_main(
        const ushort_t* __restrict__ zn,
        const float* __restrict__ pos,
        float* __restrict__ accum) {
    __shared__ float ptile[2][64 * 64];   // 2 x 16 KB pos tile

    int lane = threadIdx.x & 63;
    int w    = threadIdx.x >> 6;       // wave 0..3
    int a = w >> 1, b = w & 1;         // 0=mp, 1=sc
    int term = (a == 0) ? (b == 0 ? 2 : 0) : (b == 0 ? 1 : 3);
    int rq = lane >> 4;                // 0..3
    int lc = lane & 15;                // 0..15

    const ushort_t* Az = zn + a * (N * D);
    const ushort_t* Bz = zn + b * (N * D);

    int I0 = blockIdx.x * 64;
    int J0 = blockIdx.y * (N / JSPLIT);

    // A fragments: row = I0 + 16r + lc, k = s*32 + rq*8 .. +8 (held all loop)
    bf16x8 af[4][2];
    #pragma unroll
    for (int r = 0; r < 4; ++r)
        #pragma unroll
        for (int s = 0; s < 2; ++s)
            af[r][s] = *(const bf16x8*)(Az + (I0 + 16 * r + lc) * D + s * 32 + rq * 8);

    // per-lane running pointers (incremented per jj, offsets folded as imm)
    const ushort_t* bptr = Bz + ((size_t)(J0 + 4 * lc)) * D + rq * 8;      // + c*D + s*32
    const float*    sptr = pos + (size_t)(I0 + w * 16 + rq) * N + J0 + lc * 4;  // + it*4*N + jj*64

    // stage pos tile jj into ptile[buf]: 4 x global_load_lds_dwordx4 per wave
    #define STAGE(bufv, jjv) do {                                              \
        float* dbase_ = &ptile[bufv][w * 16 * 64];                             \
        const float* sb_ = sptr + (size_t)(jjv) * 64;                          \
        _Pragma("unroll")                                                      \
        for (int it_ = 0; it_ < 4; ++it_) {                                    \
            __builtin_amdgcn_global_load_lds(                                  \
                (g_u32*)(sb_ + (size_t)it_ * 4 * N),                           \
                (l_u32*)(dbase_ + it_ * 4 * 64), 16, 0, 0);                    \
        }                                                                      \
    } while (0)

    bf16x8 bfc[4][2], bfn[4][2];

    float rs_acc[4][4], ps_acc[4][4];
    #pragma unroll
    for (int r = 0; r < 4; ++r)
        #pragma unroll
        for (int e = 0; e < 4; ++e) { rs_acc[r][e] = 0.0f; ps_acc[r][e] = 0.0f; }

    // prologue: stage jj=0, load B-frags jj=0
    STAGE(0, 0);
    #pragma unroll
    for (int c = 0; c < 4; ++c)
        #pragma unroll
        for (int s = 0; s < 2; ++s)
            bfc[c][s] = *(const bf16x8*)(bptr + c * D + s * 32);
    __syncthreads();   // vmcnt(0) drain -> buf0 ready

    #pragma unroll 2
    for (int jj = 0; jj < JSTEPS; ++jj) {
        int buf = jj & 1;
        if (jj + 1 < JSTEPS) {
            STAGE(buf ^ 1, jj + 1);                      // async, lands by barrier
            const ushort_t* bn = bptr + 64 * D;
            #pragma unroll
            for (int c = 0; c < 4; ++c)
                #pragma unroll
                for (int s = 0; s < 2; ++s)
                    bfn[c][s] = *(const bf16x8*)(bn + c * D + s * 32);
        }

        const float* tp = &ptile[buf][rq * 4 * 64 + lc * 4];

        #pragma unroll
        for (int r = 0; r < 4; ++r) {
            f32x4 acc[4];
            #pragma unroll
            for (int c = 0; c < 4; ++c) acc[c] = (f32x4){0.f, 0.f, 0.f, 0.f};
            #pragma unroll
            for (int s = 0; s < 2; ++s)
                #pragma unroll
                for (int c = 0; c < 4; ++c)
                    acc[c] = __builtin_amdgcn_mfma_f32_16x16x32_bf16(
                        af[r][s], bfc[c][s], acc[c], 0, 0, 0);

            #pragma unroll
            for (int e = 0; e < 4; ++e) {
                f32x4 p = *(const f32x4*)(tp + (16 * r + e) * 64);  // ds_read_b128
                float rs = rs_acc[r][e], ps = ps_acc[r][e];
                #pragma unroll
                for (int c = 0; c < 4; ++c) {
                    float eV = EXP2F(acc[c][e] * TWO_OVER_LN2);
                    rs += eV;
                    ps = fmaf(eV, p[c], ps);
                }
                rs_acc[r][e] = rs; ps_acc[r][e] = ps;
            }
        }

        bptr += 64 * D;
        #pragma unroll
        for (int c = 0; c < 4; ++c)
            #pragma unroll
            for (int s = 0; s < 2; ++s)
                bfc[c][s] = bfn[c][s];
        __syncthreads();   // staging done + everyone finished reading buf
    }
    #undef STAGE

    // butterfly-reduce across the 16 lanes sharing each row (lane bits 0..3)
    #pragma unroll
    for (int r = 0; r < 4; ++r)
        #pragma unroll
        for (int e = 0; e < 4; ++e) {
            float rs = rs_acc[r][e], ps = ps_acc[r][e];
            #pragma unroll
            for (int m = 1; m < 16; m <<= 1) {
                rs += __shfl_xor(rs, m, 64);
                ps += __shfl_xor(ps, m, 64);
            }
            rs_acc[r][e] = rs; ps_acc[r][e] = ps;
        }

    if (lc == 0) {
        #pragma unroll
        for (int r = 0; r < 4; ++r)
            #pragma unroll
            for (int e = 0; e < 4; ++e) {
                int gi = I0 + 16 * r + rq * 4 + e;
                atomicAdd(&accum[term * 2 * N + gi],     rs_acc[r][e]);
                atomicAdd(&accum[term * 2 * N + N + gi], ps_acc[r][e]);
            }
    }
}

// ---------------- kernel 3: final loss reduction ------------------------
__global__ void finalize_kernel(const float* __restrict__ accum,
                                float* __restrict__ out) {
    __shared__ float red[256];
    float local = 0.0f;
    for (int i = threadIdx.x; i < N; i += 256) {
        float s = 0.0f;
        #pragma unroll
        for (int t = 0; t < 4; ++t) {
            float rs = accum[t * 2 * N + i];
            float ps = accum[t * 2 * N + N + i];
            s += logf(ps / (rs + 1e-8f));
        }
        local += s;
    }
    red[threadIdx.x] = local;
    __syncthreads();
    for (int m = 128; m; m >>= 1) {
        if (threadIdx.x < m) red[threadIdx.x] += red[threadIdx.x + m];
        __syncthreads();
    }
    if (threadIdx.x == 0) out[0] = -red[0] / (float)N;
}

extern "C" void kernel_launch(void* const* d_in, const int* in_sizes, int n_in,
                              void* d_out, int out_size, void* d_ws, size_t ws_size,
                              hipStream_t stream) {
    const float* z_mp = (const float*)d_in[0];
    const float* z_sc = (const float*)d_in[1];
    const float* pos  = (const float*)d_in[2];
    float* out = (float*)d_out;

    ushort_t* zn = (ushort_t*)d_ws;                                 // 2 MB
    float* accum = (float*)((char*)d_ws + (size_t)2 * N * D * sizeof(ushort_t));  // 256 KB

    hipMemsetAsync(accum, 0, (size_t)4 * 2 * N * sizeof(float), stream);
    normalize_kernel<<<(2 * N) / 4, 256, 0, stream>>>(z_mp, z_sc, zn);
    dim3 grid(N / 64, JSPLIT);
    contrast_main<<<grid, 256, 0, stream>>>(zn, pos, accum);
    finalize_kernel<<<1, 256, 0, stream>>>(accum, out);
}